// Round 1
// 170.422 us; speedup vs baseline: 1.0521x; 1.0521x over previous
//
#include <hip/hip_runtime.h>
#include <math.h>
#include <float.h>

#define NB 4
#define NP 4096     // points (and vertices) per batch
#define NT 8192     // triangles
#define TREC 24     // floats per triangle record (6 x float4)
#define EPSD 1e-12
// warm pass: 8 splits x 64 tris = exact min over first 512 triangles (seed)
#define WNS 8
#define WTCH 64
#define WTOT (WNS*WTCH)          // 512
// main pass: 16 splits x 480 tris over [512, 8192), plane-bound pruned
#define MNS 16
#define MTCH ((NT - WTOT)/MNS)   // 480

__device__ __forceinline__ float sigm(float x) { return 1.0f / (1.0f + expf(-x)); }

// ---------------------------------------------------------------------------
// Exact point-triangle distance^2 — EXPRESSIONS IDENTICAL to the proven
// baseline kernel (bit-identical results on the evaluated set).
// ---------------------------------------------------------------------------
__device__ __forceinline__ float tri_dist(
    float px, float py, float pz,
    float ax, float ay, float az,
    float abx, float aby, float abz,
    float acx, float acy, float acz,
    float aa, float am, float cc,
    float raa, float rcc, float rbb,
    float rden, float den, float bb, float k1)
{
  float apx = px - ax, apy = py - ay, apz = pz - az;
  float d1   = apx*abx + apy*aby + apz*abz;
  float d2   = apx*acx + apy*acy + apz*acz;
  float apap = apx*apx + apy*apy + apz*apz;
  float vb = d1*cc - d2*am;
  float vc = d2*aa - d1*am;
  float va = den - vb - vc;
  float di = apap - (vb*d1 + vc*d2)*rden;          // interior (plane projection)
  float t2 = d1 + d1;
  float tab = fminf(fmaxf(d1*raa, 0.0f), 1.0f);
  float dAB = apap + tab*(tab*aa - t2);
  float t4 = d2 + d2;
  float tac = fminf(fmaxf(d2*rcc, 0.0f), 1.0f);
  float dAC = apap + tac*(tac*cc - t4);
  float e   = d2 - d1 + k1;
  float tbc = fminf(fmaxf(e*rbb, 0.0f), 1.0f);
  float distB = apap - t2 + aa;
  float dBC = distB + tbc*(tbc*bb - (e + e));
  float m3 = fminf(fminf(dAB, dAC), dBC);
  bool in = (vb >= 0.0f) & (vc >= 0.0f) & (va > 0.0f);
  return in ? di : m3;
}

// ---------------------------------------------------------------------------
// Kernel 1: per-(batch,triangle) precompute -> 24-float record:
// q0: nx ny nz -na          (plane normal n = ab x ac, for the lower bound)
// q1: denadj ax ay az       (denadj = den*1.02 slack; 1e30 if degenerate)
// q2: abx aby abz acx
// q3: acy acz aa am
// q4: cc raa rcc rbb
// q5: rden den bb k1
// Lower bound: plane_dist^2 = (n.ap)^2/den <= dist^2 (Lagrange: |n|^2 = den).
// Degenerate (den~0): n=0 -> s=0, denadj=1e30 -> never pruned (always exact).
// ---------------------------------------------------------------------------
__global__ __launch_bounds__(256) void prep_kernel(
    const float* __restrict__ verts, const int* __restrict__ faces,
    float* __restrict__ tri)
{
  int idx = blockIdx.x * 256 + threadIdx.x;
  if (idx >= NB * NT) return;
  int b = idx >> 13;
  int t = idx & (NT - 1);
  int f0 = faces[3*t + 0], f1 = faces[3*t + 1], f2i = faces[3*t + 2];
  const float* vb_ = verts + (size_t)b * 3 * NP;
  float ax = sigm(vb_[f0]),  ay = sigm(vb_[NP + f0]),  az = sigm(vb_[2*NP + f0]);
  float bx = sigm(vb_[f1]),  by = sigm(vb_[NP + f1]),  bz = sigm(vb_[2*NP + f1]);
  float cx = sigm(vb_[f2i]), cy = sigm(vb_[NP + f2i]), cz = sigm(vb_[2*NP + f2i]);
  float abx = bx - ax, aby = by - ay, abz = bz - az;
  float acx = cx - ax, acy = cy - ay, acz = cz - az;
  double aa = (double)abx*abx + (double)aby*aby + (double)abz*abz;
  double am = (double)abx*acx + (double)aby*acy + (double)abz*acz;
  double cc = (double)acx*acx + (double)acy*acy + (double)acz*acz;
  double den = aa*cc - am*am;     // Gram determinant == |ab x ac|^2
  double bb  = aa - 2.0*am + cc;
  float raa  = (fabs(aa)  < EPSD) ? 1.0f : (float)(1.0/aa);
  float rcc  = (fabs(cc)  < EPSD) ? 1.0f : (float)(1.0/cc);
  float rbb  = (fabs(bb)  < EPSD) ? 1.0f : (float)(1.0/bb);
  float rden = (fabs(den) < EPSD) ? 0.0f : (float)(1.0/den);
  double nx = (double)aby*acz - (double)abz*acy;
  double ny = (double)abz*acx - (double)abx*acz;
  double nz = (double)abx*acy - (double)aby*acx;
  double na = nx*ax + ny*ay + nz*az;
  // 2% slack >> fp32 noise of the cancellation-prone s = n.p - n.a chain:
  // guarantees the true argmin triangle is never pruned.
  float denadj = (fabs(den) < EPSD) ? 1e30f : (float)(den * 1.02);
  float* r = tri + (size_t)idx * TREC;
  r[0]  = (float)nx; r[1]  = (float)ny; r[2]  = (float)nz; r[3] = (float)(-na);
  r[4]  = denadj;    r[5]  = ax;        r[6]  = ay;        r[7] = az;
  r[8]  = abx;       r[9]  = aby;       r[10] = abz;       r[11] = acx;
  r[12] = acy;       r[13] = acz;       r[14] = (float)aa; r[15] = (float)am;
  r[16] = (float)cc; r[17] = raa;       r[18] = rcc;       r[19] = rbb;
  r[20] = rden;      r[21] = (float)den;r[22] = (float)bb; r[23] = (float)(aa - am);
}

// ---------------------------------------------------------------------------
// Kernel 2: warm/seed pass — dense exact eval of first 512 triangles
// (8 splits x 64). One thread = one point. Wave-uniform scalar record loads
// with 1-iteration software prefetch. ~6% of brute-force work.
// ---------------------------------------------------------------------------
__global__ __launch_bounds__(256) void warm_kernel(
    const float* __restrict__ tri, const float* __restrict__ pc,
    float* __restrict__ partW)
{
  int bid  = blockIdx.x;
  int pblk = bid & 15;
  int s    = (bid >> 4) & (WNS - 1);
  int b    = bid >> 7;
  int p    = pblk * 256 + threadIdx.x;
  const float* pp = pc + ((size_t)b * NP + p) * 3;
  float px = pp[0], py = pp[1], pz = pp[2];
  const float4* R = (const float4*)(tri + ((size_t)b * NT + s * WTCH) * TREC);
  float mind = FLT_MAX;
  float4 h1 = R[1], h2 = R[2], h3 = R[3], h4 = R[4], h5 = R[5];
  for (int t = 0; t < WTCH; ++t) {
    const float4* Rn = R + 6;
    float4 g1 = Rn[1], g2 = Rn[2], g3 = Rn[3], g4 = Rn[4], g5 = Rn[5];
    float dd = tri_dist(px, py, pz,
                        h1.y, h1.z, h1.w,
                        h2.x, h2.y, h2.z,
                        h2.w, h3.x, h3.y,
                        h3.z, h3.w, h4.x,
                        h4.y, h4.z, h4.w,
                        h5.x, h5.y, h5.z, h5.w);
    mind = fminf(mind, dd);
    h1 = g1; h2 = g2; h3 = g3; h4 = g4; h5 = g5;
    R = Rn;
  }
  partW[((size_t)b * WNS + s) * NP + p] = fmaxf(mind, 0.0f);
}

// ---------------------------------------------------------------------------
// Kernel 3: pruned main pass over [512,8192). Cheap plane-bound scan
// (6 VALU/pair); survivors go through a per-wave ballot-compacted LDS ring
// queue; full-exec batch drain evaluates 64 DIFFERENT (point,tri) pairs at
// once (point coords via shfl, record gather from L2, fold via ds u32-min on
// clamped-nonnegative float bits). Prune can never skip the winner -> exact.
// ---------------------------------------------------------------------------
__global__ __launch_bounds__(256) void main_kernel(
    const float* __restrict__ tri, const float* __restrict__ pc,
    const float* __restrict__ partW, float* __restrict__ partM)
{
  __shared__ unsigned qbuf[4][128];   // per-wave candidate ring: (tri<<6)|lane
  __shared__ unsigned wmind[4][64];   // per-wave authoritative mind (float bits)

  int bid  = blockIdx.x;
  int pblk = bid & 15;
  int s    = (bid >> 4) & (MNS - 1);
  int b    = bid >> 8;
  int tid  = threadIdx.x;
  int wave = tid >> 6, lane = tid & 63;
  int p    = pblk * 256 + tid;

  const float* pp = pc + ((size_t)b * NP + p) * 3;
  float px = pp[0], py = pp[1], pz = pp[2];

  float mind = FLT_MAX;
  #pragma unroll
  for (int j = 0; j < WNS; ++j)
    mind = fminf(mind, partW[((size_t)b * WNS + j) * NP + p]);
  wmind[wave][lane] = __float_as_uint(mind);   // >= 0, so u32 order == f32 order

  unsigned qcnt = 0u, qd = 0u;                 // wave-uniform (ballot-derived)
  const float* triB = tri + (size_t)b * NT * TREC;
  int tg0 = WTOT + s * MTCH;
  const float4* Rf = (const float4*)(triB + (size_t)tg0 * TREC);

#define DRAIN_BATCH(NACT)                                                     \
  {                                                                           \
    unsigned ent = qbuf[wave][(qd + (unsigned)lane) & 127u];                  \
    if ((unsigned)lane < (unsigned)(NACT)) {                                  \
      int te  = (int)(ent >> 6);                                              \
      int src = (int)(ent & 63u);                                             \
      float qx = __shfl(px, src, 64);                                         \
      float qy = __shfl(py, src, 64);                                         \
      float qz = __shfl(pz, src, 64);                                         \
      const float* rr = triB + (size_t)te * TREC;                             \
      float4 w1 = *(const float4*)(rr + 4);                                   \
      float4 w2 = *(const float4*)(rr + 8);                                   \
      float4 w3 = *(const float4*)(rr + 12);                                  \
      float4 w4 = *(const float4*)(rr + 16);                                  \
      float4 w5 = *(const float4*)(rr + 20);                                  \
      float dd = fmaxf(tri_dist(qx, qy, qz,                                   \
                                w1.y, w1.z, w1.w,                             \
                                w2.x, w2.y, w2.z,                             \
                                w2.w, w3.x, w3.y,                             \
                                w3.z, w3.w, w4.x,                             \
                                w4.y, w4.z, w4.w,                             \
                                w5.x, w5.y, w5.z, w5.w), 0.0f);               \
      atomicMin(&wmind[wave][src], __float_as_uint(dd));                      \
    }                                                                         \
    qd += (unsigned)(NACT);                                                   \
    mind = fminf(mind, __uint_as_float(wmind[wave][lane]));                   \
  }

#define SCAN_ITER(Q0, DA, TIDX)                                               \
  {                                                                           \
    float sN = fmaf(pz, (Q0).z, fmaf(py, (Q0).y, fmaf(px, (Q0).x, (Q0).w)));  \
    bool pred = (sN * sN) < (mind * (DA));                                    \
    unsigned long long mask = __ballot(pred);                                 \
    if (mask) {                                                               \
      if (pred) {                                                             \
        int prefix = __builtin_amdgcn_mbcnt_hi((unsigned)(mask >> 32),        \
                       __builtin_amdgcn_mbcnt_lo((unsigned)mask, 0));         \
        qbuf[wave][(qcnt + (unsigned)prefix) & 127u] =                        \
            ((unsigned)(TIDX) << 6) | (unsigned)lane;                         \
      }                                                                       \
      qcnt += (unsigned)__builtin_popcountll(mask);                           \
      if (qcnt - qd >= 64u) DRAIN_BATCH(64u);                                 \
    }                                                                         \
  }

  // group-of-4 scan with 1-group-ahead header prefetch (wave-uniform s_loads)
  float4 c00 = Rf[0],  c01 = Rf[1],  c10 = Rf[6],  c11 = Rf[7];
  float4 c20 = Rf[12], c21 = Rf[13], c30 = Rf[18], c31 = Rf[19];
  int tg = tg0;
  for (int g = 0; g < MTCH / 4; ++g) {
    const float4* Rn = Rf + 24;
    float4 n00 = Rn[0],  n01 = Rn[1],  n10 = Rn[6],  n11 = Rn[7];
    float4 n20 = Rn[12], n21 = Rn[13], n30 = Rn[18], n31 = Rn[19];
    SCAN_ITER(c00, c01.x, tg + 0);
    SCAN_ITER(c10, c11.x, tg + 1);
    SCAN_ITER(c20, c21.x, tg + 2);
    SCAN_ITER(c30, c31.x, tg + 3);
    c00 = n00; c01 = n01; c10 = n10; c11 = n11;
    c20 = n20; c21 = n21; c30 = n30; c31 = n31;
    Rf = Rn; tg += 4;
  }

  // final partial drain (pending <= 63 by construction)
  unsigned pend = qcnt - qd;
  if (pend) DRAIN_BATCH(pend);
  mind = fminf(mind, __uint_as_float(wmind[wave][lane]));

  partM[((size_t)b * MNS + s) * NP + p] = fmaxf(mind, 0.0f);

#undef SCAN_ITER
#undef DRAIN_BATCH
}

// ---------------------------------------------------------------------------
// Kernel 4: parallel reduce over the MNS main partials (each already folds
// the warm seed). 64 blocks (16/batch) x 256 threads.
// ---------------------------------------------------------------------------
__global__ __launch_bounds__(256) void reduce_kernel(
    const float* __restrict__ part, const float* __restrict__ pc,
    float* __restrict__ bl2)
{
  int blk = blockIdx.x;
  int b = blk >> 4;
  int p = (blk & 15) * 256 + threadIdx.x;
  float m = FLT_MAX;
  #pragma unroll
  for (int s = 0; s < MNS; ++s)
    m = fminf(m, part[((size_t)b * MNS + s) * NP + p]);
  const float* pp = pc + ((size_t)b * NP + p) * 3;
  float x = pp[0], y = pp[1], z = pp[2];
  float msk = ((x != 0.0f) | (y != 0.0f) | (z != 0.0f)) ? 1.0f : 0.0f;
  float sdm = m * msk, sm = msk;
  for (int off = 32; off > 0; off >>= 1) {
    sdm += __shfl_down(sdm, off, 64);
    sm  += __shfl_down(sm,  off, 64);
  }
  __shared__ float s1[4], s2[4];
  int wave = threadIdx.x >> 6, lanei = threadIdx.x & 63;
  if (lanei == 0) { s1[wave] = sdm; s2[wave] = sm; }
  __syncthreads();
  if (threadIdx.x == 0) {
    bl2[2 * blk]     = s1[0] + s1[1] + s1[2] + s1[3];
    bl2[2 * blk + 1] = s2[0] + s2[1] + s2[2] + s2[3];
  }
}

__global__ void final_kernel(const float* __restrict__ bl2, float* __restrict__ out)
{
  if (threadIdx.x == 0 && blockIdx.x == 0) {
    float acc = 0.0f;
    for (int b = 0; b < NB; ++b) {
      float sdm = 0.0f, sm = 0.0f;
      for (int k = 0; k < 16; ++k) {
        sdm += bl2[2 * (b * 16 + k)];
        sm  += bl2[2 * (b * 16 + k) + 1];
      }
      acc += sdm / fmaxf(sm, 1.0f);
    }
    out[0] = 0.25f * acc;
  }
}

extern "C" void kernel_launch(void* const* d_in, const int* in_sizes, int n_in,
                              void* d_out, int out_size, void* d_ws, size_t ws_size,
                              hipStream_t stream) {
  const float* verts = (const float*)d_in[0];   // (4,3,16,16,16) f32
  const float* pc    = (const float*)d_in[1];   // (4,4096,3) f32
  const int*   faces = (const int*)d_in[2];     // (8192,3) i32
  float* out = (float*)d_out;

  float* tri   = (float*)d_ws;                       // NB*NT*TREC = 786432 floats
  float* partW = tri   + (size_t)NB * NT * TREC;     // NB*WNS*NP = 131072
  float* partM = partW + (size_t)NB * WNS * NP;      // NB*MNS*NP = 262144
  float* bl2   = partM + (size_t)NB * MNS * NP;      // 128

  prep_kernel<<<(NB * NT) / 256, 256, 0, stream>>>(verts, faces, tri);
  warm_kernel<<<NB * WNS * 16, 256, 0, stream>>>(tri, pc, partW);
  main_kernel<<<NB * MNS * 16, 256, 0, stream>>>(tri, pc, partW, partM);
  reduce_kernel<<<NB * 16, 256, 0, stream>>>(partM, pc, bl2);
  final_kernel<<<1, 64, 0, stream>>>(bl2, out);
}

// Round 2
// 164.435 us; speedup vs baseline: 1.0904x; 1.0364x over previous
//
#include <hip/hip_runtime.h>
#include <math.h>
#include <float.h>

#define NB 4
#define NP 4096     // points (and vertices) per batch
#define NT 8192     // triangles
#define TSE 12      // floats per scan record  (3 x float4)
#define TEE 20      // floats per eval record  (5 x float4)
#define EPSD 1e-12
#define MNS 32      // main-pass splits
#define MTCH (NT/MNS)   // 256 triangles per split
#define VCH 16      // seed vertex chunks
#define VLEN (NP/VCH)   // 256 vertices per chunk

__device__ __forceinline__ float sigm(float x) { return 1.0f / (1.0f + expf(-x)); }

// ---------------------------------------------------------------------------
// Exact point-triangle distance^2 — EXPRESSIONS IDENTICAL to the proven
// baseline kernel (bit-identical results on the evaluated set).
// ---------------------------------------------------------------------------
__device__ __forceinline__ float tri_dist(
    float px, float py, float pz,
    float ax, float ay, float az,
    float abx, float aby, float abz,
    float acx, float acy, float acz,
    float aa, float am, float cc,
    float raa, float rcc, float rbb,
    float rden, float den, float bb, float k1)
{
  float apx = px - ax, apy = py - ay, apz = pz - az;
  float d1   = apx*abx + apy*aby + apz*abz;
  float d2   = apx*acx + apy*acy + apz*acz;
  float apap = apx*apx + apy*apy + apz*apz;
  float vb = d1*cc - d2*am;
  float vc = d2*aa - d1*am;
  float va = den - vb - vc;
  float di = apap - (vb*d1 + vc*d2)*rden;          // interior (plane projection)
  float t2 = d1 + d1;
  float tab = fminf(fmaxf(d1*raa, 0.0f), 1.0f);
  float dAB = apap + tab*(tab*aa - t2);
  float t4 = d2 + d2;
  float tac = fminf(fmaxf(d2*rcc, 0.0f), 1.0f);
  float dAC = apap + tac*(tac*cc - t4);
  float e   = d2 - d1 + k1;
  float tbc = fminf(fmaxf(e*rbb, 0.0f), 1.0f);
  float distB = apap - t2 + aa;
  float dBC = distB + tbc*(tbc*bb - (e + e));
  float m3 = fminf(fminf(dAB, dAC), dBC);
  bool in = (vb >= 0.0f) & (vc >= 0.0f) & (va > 0.0f);
  return in ? di : m3;
}

// ---------------------------------------------------------------------------
// Kernel 0: elementwise sigmoid of all vertices -> pos (same (B,3,NP) layout)
// ---------------------------------------------------------------------------
__global__ __launch_bounds__(256) void vert_kernel(
    const float* __restrict__ verts, float* __restrict__ pos)
{
  int i = blockIdx.x * 256 + threadIdx.x;
  if (i < NB * 3 * NP) pos[i] = sigm(verts[i]);
}

// ---------------------------------------------------------------------------
// Kernel 1: per-(batch,triangle) precompute.
// triS (12 floats, scan):  [nhx nhy nhz w | lox loy loz hix | hiy hiz 0 0]
//   n-hat = (ab x ac)/sqrt(den*1.02)  (slack baked in), w = -nhat . a
//   plane LB test: s = nhat.p + w; survive iff s^2 < mind (+eps)
//   AABB LB: dist^2(p, [lo,hi]) <= dist^2(p, tri)
// triE (20 floats, eval):  [ax ay az abx | aby abz acx acy | acz aa am cc |
//                           raa rcc rbb rden | den bb k1 0]
// Degenerate (den~0): nhat=0, w=0 -> s=0 -> plane never prunes; box still valid.
// ---------------------------------------------------------------------------
__global__ __launch_bounds__(256) void prep_kernel(
    const float* __restrict__ pos, const int* __restrict__ faces,
    float* __restrict__ triS, float* __restrict__ triE)
{
  int idx = blockIdx.x * 256 + threadIdx.x;
  if (idx >= NB * NT) return;
  int b = idx >> 13;
  int t = idx & (NT - 1);
  int f0 = faces[3*t + 0], f1 = faces[3*t + 1], f2i = faces[3*t + 2];
  const float* pb = pos + (size_t)b * 3 * NP;
  float ax = pb[f0],  ay = pb[NP + f0],  az = pb[2*NP + f0];
  float bx = pb[f1],  by = pb[NP + f1],  bz = pb[2*NP + f1];
  float cx = pb[f2i], cy = pb[NP + f2i], cz = pb[2*NP + f2i];
  float abx = bx - ax, aby = by - ay, abz = bz - az;
  float acx = cx - ax, acy = cy - ay, acz = cz - az;
  double aa = (double)abx*abx + (double)aby*aby + (double)abz*abz;
  double am = (double)abx*acx + (double)aby*acy + (double)abz*acz;
  double cc = (double)acx*acx + (double)acy*acy + (double)acz*acz;
  double den = aa*cc - am*am;     // Gram determinant == |ab x ac|^2
  double bb  = aa - 2.0*am + cc;
  float raa  = (fabs(aa)  < EPSD) ? 1.0f : (float)(1.0/aa);
  float rcc  = (fabs(cc)  < EPSD) ? 1.0f : (float)(1.0/cc);
  float rbb  = (fabs(bb)  < EPSD) ? 1.0f : (float)(1.0/bb);
  float rden = (fabs(den) < EPSD) ? 0.0f : (float)(1.0/den);
  double nx = (double)aby*acz - (double)abz*acy;
  double ny = (double)abz*acx - (double)abx*acz;
  double nz = (double)abx*acy - (double)aby*acx;
  // normalize with 2% slack baked in; degenerate -> zero normal (never prunes)
  double rs = (fabs(den) < EPSD) ? 0.0 : 1.0 / sqrt(den * 1.02);
  float nhx = (float)(nx * rs), nhy = (float)(ny * rs), nhz = (float)(nz * rs);
  float w = (float)(-(nx*ax + ny*ay + nz*az) * rs);
  float lox = fminf(ax, fminf(bx, cx)), hix = fmaxf(ax, fmaxf(bx, cx));
  float loy = fminf(ay, fminf(by, cy)), hiy = fmaxf(ay, fmaxf(by, cy));
  float loz = fminf(az, fminf(bz, cz)), hiz = fmaxf(az, fmaxf(bz, cz));
  float* rs_ = triS + (size_t)idx * TSE;
  rs_[0] = nhx; rs_[1] = nhy; rs_[2] = nhz; rs_[3]  = w;
  rs_[4] = lox; rs_[5] = loy; rs_[6] = loz; rs_[7]  = hix;
  rs_[8] = hiy; rs_[9] = hiz; rs_[10] = 0.0f; rs_[11] = 0.0f;
  float* re = triE + (size_t)idx * TEE;
  re[0]  = ax;  re[1]  = ay;  re[2]  = az;  re[3]  = abx;
  re[4]  = aby; re[5]  = abz; re[6]  = acx; re[7]  = acy;
  re[8]  = acz; re[9]  = (float)aa; re[10] = (float)am; re[11] = (float)cc;
  re[12] = raa; re[13] = rcc; re[14] = rbb; re[15] = rden;
  re[16] = (float)den; re[17] = (float)bb; re[18] = (float)(aa - am); re[19] = 0.0f;
}

// ---------------------------------------------------------------------------
// Kernel 2: vertex-distance seed. mind0(p) = min_v |p - v|^2 over a 256-vertex
// chunk. |p-v|^2 >= dist(p, any triangle containing v) >= true min -> valid
// pruning threshold AND exact to fold into the output min. Wave-uniform
// s_load streaming of vertex coords (SoA by axis).
// ---------------------------------------------------------------------------
__global__ __launch_bounds__(256) void seed_kernel(
    const float* __restrict__ pos, const float* __restrict__ pc,
    float* __restrict__ partS)
{
  int bid  = blockIdx.x;
  int pblk = bid & 15;
  int vc   = (bid >> 4) & (VCH - 1);
  int b    = bid >> 8;
  int p    = pblk * 256 + threadIdx.x;
  const float* pp = pc + ((size_t)b * NP + p) * 3;
  float px = pp[0], py = pp[1], pz = pp[2];
  const float* base = pos + (size_t)b * 3 * NP + vc * VLEN;
  const float4* X = (const float4*)(base);
  const float4* Y = (const float4*)(base + NP);
  const float4* Z = (const float4*)(base + 2 * NP);
  float m = FLT_MAX;
  #pragma unroll 4
  for (int v = 0; v < VLEN / 4; ++v) {
    float4 vx = X[v], vy = Y[v], vz = Z[v];
    {
      float dx = px - vx.x, dy = py - vy.x, dz = pz - vz.x;
      m = fminf(m, dx*dx + dy*dy + dz*dz);
    }
    {
      float dx = px - vx.y, dy = py - vy.y, dz = pz - vz.y;
      m = fminf(m, dx*dx + dy*dy + dz*dz);
    }
    {
      float dx = px - vx.z, dy = py - vy.z, dz = pz - vz.z;
      m = fminf(m, dx*dx + dy*dy + dz*dz);
    }
    {
      float dx = px - vx.w, dy = py - vy.w, dz = pz - vz.w;
      m = fminf(m, dx*dx + dy*dy + dz*dz);
    }
  }
  partS[((size_t)b * VCH + vc) * NP + p] = m;
}

// ---------------------------------------------------------------------------
// Kernel 3: pruned main pass over all NT triangles (32 splits x 256).
// Cheap scan = plane-slab AND AABB lower bounds (~20 VALU/pair); survivors go
// through the per-wave ballot-compacted LDS ring queue; full-exec batch drain
// evaluates 64 different (point,tri) pairs at once. Argmin is never pruned
// -> min over evaluated exacts (+ vertex seed, which is >= true min) is exact.
// ---------------------------------------------------------------------------
__global__ __launch_bounds__(256) void main_kernel(
    const float* __restrict__ triS, const float* __restrict__ triE,
    const float* __restrict__ pc, const float* __restrict__ partS,
    float* __restrict__ partM)
{
  __shared__ unsigned qbuf[4][128];   // per-wave candidate ring: (tri<<6)|lane
  __shared__ unsigned wmind[4][64];   // per-wave authoritative mind (float bits)

  int bid  = blockIdx.x;
  int pblk = bid & 15;
  int s    = (bid >> 4) & (MNS - 1);
  int b    = bid >> 9;
  int tid  = threadIdx.x;
  int wave = tid >> 6, lane = tid & 63;
  int p    = pblk * 256 + tid;

  const float* pp = pc + ((size_t)b * NP + p) * 3;
  float px = pp[0], py = pp[1], pz = pp[2];

  float mind = FLT_MAX;
  #pragma unroll
  for (int j = 0; j < VCH; ++j)
    mind = fminf(mind, partS[((size_t)b * VCH + j) * NP + p]);
  wmind[wave][lane] = __float_as_uint(mind);   // >= 0, so u32 order == f32 order
  float mth = mind + 1e-8f;                    // absolute cushion on the bounds

  unsigned qcnt = 0u, qd = 0u;                 // wave-uniform (ballot-derived)
  const float* triEB = triE + (size_t)b * NT * TEE;
  int tg0 = s * MTCH;
  const float4* Rs = (const float4*)(triS + (size_t)(b * NT + tg0) * TSE);

#define DRAIN_BATCH(NACT)                                                     \
  {                                                                           \
    unsigned ent = qbuf[wave][(qd + (unsigned)lane) & 127u];                  \
    if ((unsigned)lane < (unsigned)(NACT)) {                                  \
      int te  = (int)(ent >> 6);                                              \
      int src = (int)(ent & 63u);                                             \
      float qx = __shfl(px, src, 64);                                         \
      float qy = __shfl(py, src, 64);                                         \
      float qz = __shfl(pz, src, 64);                                         \
      const float* rr = triEB + (size_t)te * TEE;                             \
      float4 w1 = *(const float4*)(rr + 0);                                   \
      float4 w2 = *(const float4*)(rr + 4);                                   \
      float4 w3 = *(const float4*)(rr + 8);                                   \
      float4 w4 = *(const float4*)(rr + 12);                                  \
      float4 w5 = *(const float4*)(rr + 16);                                  \
      float dd = fmaxf(tri_dist(qx, qy, qz,                                   \
                                w1.x, w1.y, w1.z,                             \
                                w1.w, w2.x, w2.y,                             \
                                w2.z, w2.w, w3.x,                             \
                                w3.y, w3.z, w3.w,                             \
                                w4.x, w4.y, w4.z,                             \
                                w4.w, w5.x, w5.y, w5.z), 0.0f);               \
      atomicMin(&wmind[wave][src], __float_as_uint(dd));                      \
    }                                                                         \
    qd += (unsigned)(NACT);                                                   \
    mind = fminf(mind, __uint_as_float(wmind[wave][lane]));                   \
    mth  = mind + 1e-8f;                                                      \
  }

// q0 = [nhx nhy nhz w], q1 = [lox loy loz hix], q2 = [hiy hiz - -]
#define SCAN_ITER(Q0, Q1, Q2, TIDX)                                           \
  {                                                                           \
    float sN = fmaf(pz, (Q0).z, fmaf(py, (Q0).y, fmaf(px, (Q0).x, (Q0).w)));  \
    float dx = fmaxf(fmaxf((Q1).x - px, px - (Q1).w), 0.0f);                  \
    float dy = fmaxf(fmaxf((Q1).y - py, py - (Q2).x), 0.0f);                  \
    float dz = fmaxf(fmaxf((Q1).z - pz, pz - (Q2).y), 0.0f);                  \
    float bb2 = dx*dx + dy*dy + dz*dz;                                        \
    bool pred = (sN * sN < mth) & (bb2 * 0.98f < mth);                        \
    unsigned long long mask = __ballot(pred);                                 \
    if (mask) {                                                               \
      if (pred) {                                                             \
        int prefix = __builtin_amdgcn_mbcnt_hi((unsigned)(mask >> 32),        \
                       __builtin_amdgcn_mbcnt_lo((unsigned)mask, 0));         \
        qbuf[wave][(qcnt + (unsigned)prefix) & 127u] =                        \
            ((unsigned)(TIDX) << 6) | (unsigned)lane;                         \
      }                                                                       \
      qcnt += (unsigned)__builtin_popcountll(mask);                           \
      if (qcnt - qd >= 64u) DRAIN_BATCH(64u);                                 \
    }                                                                         \
  }

  // group-of-2 scan with 1-group-ahead prefetch (wave-uniform s_loads).
  // Last group prefetches past the split end — stays inside triS/triE
  // workspace (contiguous), values unused.
  float4 a0 = Rs[0], a1 = Rs[1], a2 = Rs[2];
  float4 b0 = Rs[3], b1 = Rs[4], b2 = Rs[5];
  int tg = tg0;
  for (int g = 0; g < MTCH / 2; ++g) {
    const float4* Rn = Rs + 6;
    float4 c0 = Rn[0], c1 = Rn[1], c2 = Rn[2];
    float4 d0 = Rn[3], d1 = Rn[4], d2 = Rn[5];
    SCAN_ITER(a0, a1, a2, tg + 0);
    SCAN_ITER(b0, b1, b2, tg + 1);
    a0 = c0; a1 = c1; a2 = c2;
    b0 = d0; b1 = d1; b2 = d2;
    Rs = Rn; tg += 2;
  }

  // final partial drain (pending <= 63 by construction)
  unsigned pend = qcnt - qd;
  if (pend) DRAIN_BATCH(pend);
  mind = fminf(mind, __uint_as_float(wmind[wave][lane]));

  partM[((size_t)b * MNS + s) * NP + p] = fmaxf(mind, 0.0f);

#undef SCAN_ITER
#undef DRAIN_BATCH
}

// ---------------------------------------------------------------------------
// Kernel 4: parallel reduce over the MNS main partials (each already folds
// the vertex seed). 64 blocks (16/batch) x 256 threads.
// ---------------------------------------------------------------------------
__global__ __launch_bounds__(256) void reduce_kernel(
    const float* __restrict__ part, const float* __restrict__ pc,
    float* __restrict__ bl2)
{
  int blk = blockIdx.x;
  int b = blk >> 4;
  int p = (blk & 15) * 256 + threadIdx.x;
  float m = FLT_MAX;
  #pragma unroll
  for (int s = 0; s < MNS; ++s)
    m = fminf(m, part[((size_t)b * MNS + s) * NP + p]);
  const float* pp = pc + ((size_t)b * NP + p) * 3;
  float x = pp[0], y = pp[1], z = pp[2];
  float msk = ((x != 0.0f) | (y != 0.0f) | (z != 0.0f)) ? 1.0f : 0.0f;
  float sdm = m * msk, sm = msk;
  for (int off = 32; off > 0; off >>= 1) {
    sdm += __shfl_down(sdm, off, 64);
    sm  += __shfl_down(sm,  off, 64);
  }
  __shared__ float s1[4], s2[4];
  int wave = threadIdx.x >> 6, lanei = threadIdx.x & 63;
  if (lanei == 0) { s1[wave] = sdm; s2[wave] = sm; }
  __syncthreads();
  if (threadIdx.x == 0) {
    bl2[2 * blk]     = s1[0] + s1[1] + s1[2] + s1[3];
    bl2[2 * blk + 1] = s2[0] + s2[1] + s2[2] + s2[3];
  }
}

__global__ void final_kernel(const float* __restrict__ bl2, float* __restrict__ out)
{
  if (threadIdx.x == 0 && blockIdx.x == 0) {
    float acc = 0.0f;
    for (int b = 0; b < NB; ++b) {
      float sdm = 0.0f, sm = 0.0f;
      for (int k = 0; k < 16; ++k) {
        sdm += bl2[2 * (b * 16 + k)];
        sm  += bl2[2 * (b * 16 + k) + 1];
      }
      acc += sdm / fmaxf(sm, 1.0f);
    }
    out[0] = 0.25f * acc;
  }
}

extern "C" void kernel_launch(void* const* d_in, const int* in_sizes, int n_in,
                              void* d_out, int out_size, void* d_ws, size_t ws_size,
                              hipStream_t stream) {
  const float* verts = (const float*)d_in[0];   // (4,3,16,16,16) f32
  const float* pc    = (const float*)d_in[1];   // (4,4096,3) f32
  const int*   faces = (const int*)d_in[2];     // (8192,3) i32
  float* out = (float*)d_out;

  float* pos   = (float*)d_ws;                        // NB*3*NP   =   49152 floats
  float* triS  = pos   + (size_t)NB * 3 * NP;         // NB*NT*12  =  393216
  float* triE  = triS  + (size_t)NB * NT * TSE;       // NB*NT*20  =  655360
  float* partS = triE  + (size_t)NB * NT * TEE;       // NB*VCH*NP =  262144
  float* partM = partS + (size_t)NB * VCH * NP;       // NB*MNS*NP =  524288
  float* bl2   = partM + (size_t)NB * MNS * NP;       // 128

  vert_kernel<<<(NB * 3 * NP) / 256, 256, 0, stream>>>(verts, pos);
  prep_kernel<<<(NB * NT) / 256, 256, 0, stream>>>(pos, faces, triS, triE);
  seed_kernel<<<NB * VCH * 16, 256, 0, stream>>>(pos, pc, partS);
  main_kernel<<<NB * MNS * 16, 256, 0, stream>>>(triS, triE, pc, partS, partM);
  reduce_kernel<<<NB * 16, 256, 0, stream>>>(partM, pc, bl2);
  final_kernel<<<1, 64, 0, stream>>>(bl2, out);
}